// Round 10
// baseline (55.996 us; speedup 1.0000x reference)
//
#include <hip/hip_runtime.h>
#include <hip/hip_fp16.h>

// Joint bilateral filter block — 4-wave cooperative, thread-per-patch,
// row-aligned fp16 LDS tile, packed v_dot2_f32_f16 conv1.
// x (1,1,20,96,96) f32; guide_im (N,343) f32, N = 16*96*96 = 147456;
// out n = dd*9216 + h*96 + w uses x depths dd+1..dd+3, H/W zero-pad.
//
// History: r4 52.5us (4xb32 rows); r9 51.4us (b128 rows). r5-r8 (8-wave /
// persistent / reg-prefetch) all regressed (VGPR spill or wave lockstep).
// This round: conv1 consumed PACKED (fdot2 + alignbit) -> per-patch VALU
// stream 5100 -> ~3450 ops; LDS/occupancy/staging identical to r9.

#define NPATCH 147456
#define TPB     256        // 4 waves
#define PPB      64        // patches per block (one per lane, all waves share)
#define NBLK   (NPATCH / PPB)   // 2304
#define ROW_H     8        // halves per row: 7 data + 1 zero pad (16 B aligned)
#define PATCH_H 392        // 49 rows * 8 halves = 784 B per patch
#define PATCH_D 196        // dwords per patch
#define NF4    5488        // float4s per 64-patch tile (64*343/4)

typedef _Float16 h2_t __attribute__((ext_vector_type(2)));

// ---------------- Kernel A: domain branch (runs once, 1 block) --------------
__global__ __launch_bounds__(128) void domain_branch_kernel(
    const float* __restrict__ dn,
    const float* __restrict__ w1, const float* __restrict__ b1,
    const float* __restrict__ w2, const float* __restrict__ b2,
    float* __restrict__ dom_out)
{
    __shared__ float s_in[344];
    __shared__ float s_c1[128];
    const int t = threadIdx.x;
    for (int idx = t; idx < 343; idx += 128) s_in[idx] = dn[idx];
    __syncthreads();
    if (t < 125) {
        const int i = t / 25, j = (t / 5) % 5, k = t % 5;
        float acc = b1[0];
        const float* base = &s_in[i * 49 + j * 7 + k];
#pragma unroll
        for (int dz = 0; dz < 3; ++dz)
#pragma unroll
            for (int dy = 0; dy < 3; ++dy)
#pragma unroll
                for (int dx = 0; dx < 3; ++dx)
                    acc = fmaf(base[dz * 49 + dy * 7 + dx], w1[dz * 9 + dy * 3 + dx], acc);
        s_c1[t] = fmaxf(acc, 0.f);
    }
    __syncthreads();
    if (t < 27) {
        const int dz = t / 9, dy = (t / 3) % 3, dx = t % 3;
        float acc = b2[0];
#pragma unroll
        for (int u = 0; u < 3; ++u)
#pragma unroll
            for (int v = 0; v < 3; ++v)
#pragma unroll
                for (int q = 0; q < 3; ++q)
                    acc = fmaf(s_c1[(dz + u) * 25 + (dy + v) * 5 + (dx + q)],
                               w2[u * 9 + v * 3 + q], acc);
        dom_out[t] = fmaxf(acc, 0.f);
    }
}

// ---------------- helpers ----------------
__device__ __forceinline__ unsigned short f2h(float f) {
    return __half_as_ushort(__float2half(f));
}
__device__ __forceinline__ float fdot2(unsigned int a, unsigned int b, float c) {
    return __builtin_amdgcn_fdot2(__builtin_bit_cast(h2_t, a),
                                  __builtin_bit_cast(h2_t, b), c, false);
}

// Load row y of absolute z-slice zi (16B-aligned, 8-half rows) packed:
// q[0..3] = {h0h1, h2h3, h4h5, h6h7(pad=0)}, r[0..1] = {h1h2, h3h4}.
__device__ __forceinline__ void load_row_pk(const unsigned int* __restrict__ P,
                                            unsigned int* q, unsigned int* r,
                                            int zi, int y) {
    const int d0 = zi * 28 + y * 4;        // dword offset, multiple of 4 -> 16B
    const uint4 v = *reinterpret_cast<const uint4*>(P + d0);
    q[0] = v.x; q[1] = v.y; q[2] = v.z; q[3] = v.w;
    r[0] = __builtin_amdgcn_alignbit(v.y, v.x, 16);   // {h1,h2}
    r[1] = __builtin_amdgcn_alignbit(v.z, v.y, 16);   // {h3,h4}
}

// Run conv1+fused-conv2 row-tasks (i,j) from (IB,JB) to (IE,JE) inclusive,
// accumulating into a2 (partial). wa={W0,W1}, wb={W2,0}, wc={0,W2} per (u,v).
template<int IB, int JB, int IE, int JE>
__device__ __forceinline__ void run_tasks(const unsigned int* __restrict__ P,
                                          const unsigned int* wa,
                                          const unsigned int* wb,
                                          const unsigned int* wc, float bb1,
                                          const float* __restrict__ w2,
                                          float (&a2)[3][3][3])
{
#pragma unroll
    for (int i = IB; i <= IE; ++i) {              // c1 z-slab (input slices i..i+2)
        unsigned int rq[3][3][4];                 // [u][y%3] packed pairs
        unsigned int rr[3][3][2];                 // [u][y%3] shifted pairs
        const int j0 = (i == IB) ? JB : 0;
        const int j1 = (i == IE) ? JE : 4;
#pragma unroll
        for (int j = j0; j <= j1; ++j) {
            if (j == j0) {
#pragma unroll
                for (int u = 0; u < 3; ++u)
#pragma unroll
                    for (int dy = 0; dy < 3; ++dy)
                        load_row_pk(P, rq[u][(j + dy) % 3], rr[u][(j + dy) % 3],
                                    i + u, j + dy);
            } else {
#pragma unroll
                for (int u = 0; u < 3; ++u)
                    load_row_pk(P, rq[u][(j + 2) % 3], rr[u][(j + 2) % 3],
                                i + u, j + 2);
            }

            // c1 row (i, j, k=0..4) via packed dot2
            float c1r[5];
#pragma unroll
            for (int k = 0; k < 5; ++k) c1r[k] = bb1;
#pragma unroll
            for (int u = 0; u < 3; ++u)
#pragma unroll
                for (int v = 0; v < 3; ++v) {
                    const unsigned int* Q = rq[u][(j + v) % 3];
                    const unsigned int* R = rr[u][(j + v) % 3];
                    const int uv = u * 3 + v;
                    c1r[0] = fdot2(Q[0], wa[uv], c1r[0]);
                    c1r[0] = fdot2(Q[1], wb[uv], c1r[0]);
                    c1r[1] = fdot2(R[0], wa[uv], c1r[1]);
                    c1r[1] = fdot2(Q[1], wc[uv], c1r[1]);
                    c1r[2] = fdot2(Q[1], wa[uv], c1r[2]);
                    c1r[2] = fdot2(Q[2], wb[uv], c1r[2]);
                    c1r[3] = fdot2(R[1], wa[uv], c1r[3]);
                    c1r[3] = fdot2(Q[2], wc[uv], c1r[3]);
                    c1r[4] = fdot2(Q[2], wa[uv], c1r[4]);
                    c1r[4] = fdot2(Q[3], wb[uv], c1r[4]);
                }
#pragma unroll
            for (int k = 0; k < 5; ++k) c1r[k] = fmaxf(c1r[k], 0.f);

            // fused conv2 accumulation
#pragma unroll
            for (int dz2 = 0; dz2 < 3; ++dz2) {
                const int u2 = i - dz2;
                if (u2 >= 0 && u2 < 3) {
#pragma unroll
                    for (int v2 = 0; v2 < 3; ++v2) {
                        const int dy2 = j - v2;
                        if (dy2 >= 0 && dy2 < 3) {
#pragma unroll
                            for (int dx2 = 0; dx2 < 3; ++dx2)
#pragma unroll
                                for (int q = 0; q < 3; ++q)
                                    a2[dz2][dy2][dx2] =
                                        fmaf(c1r[dx2 + q],
                                             w2[u2 * 9 + v2 * 3 + q],
                                             a2[dz2][dy2][dx2]);
                        }
                    }
                }
            }
        }
    }
}

// ---------------- Kernel B: range branch + bilateral combine ----------------
__global__ __launch_bounds__(TPB, 3) void jbf_main_kernel(
    const float* __restrict__ guide, const float* __restrict__ x,
    const float* __restrict__ w1, const float* __restrict__ b1,
    const float* __restrict__ w2, const float* __restrict__ b2,
    const float* __restrict__ dom, float* __restrict__ out)
{
    // partials buffer aliases the (dead-by-then) patch tile: 50,176 B total
    union SM {
        unsigned short tile[PPB * PATCH_H];   // 50,176 B
        float part[3][PPB][27];               // 20,736 B
    };
    __shared__ SM sm;

    const int tid  = threadIdx.x;
    const int wid  = tid >> 6;      // wave 0..3
    const int lane = tid & 63;      // patch owned by this thread
    const int blk  = blockIdx.x;

    // ---- packed conv1 weights (wave-uniform) ----
    unsigned int wa[9], wb[9], wc[9];
#pragma unroll
    for (int uv = 0; uv < 9; ++uv) {
        const unsigned int h0 = f2h(w1[uv * 3 + 0]);
        const unsigned int h1 = f2h(w1[uv * 3 + 1]);
        const unsigned int h2 = f2h(w1[uv * 3 + 2]);
        wa[uv] = h0 | (h1 << 16);
        wb[uv] = h2;            // {W2, 0}
        wc[uv] = h2 << 16;      // {0, W2}
    }

    // ============== stage 64 patches (21952 f32, contiguous) -> fp16 LDS ===
    // element (p, e) -> row r = e/7, x = e%7; dst = p*392 + r*8 + x
    const float4* __restrict__ src =
        reinterpret_cast<const float4*>(guide + (size_t)blk * (PPB * 343));

    // zero the h7 pads (read by dot2 against a 0 weight; LDS is undefined)
    for (int idx = tid; idx < PPB * 49; idx += TPB) {
        const int p = idx / 49, r = idx - p * 49;
        sm.tile[p * PATCH_H + r * ROW_H + 7] = 0;
    }

#define STORE4(IT, C) do {                                       \
        int flat = (IT) * (TPB * 4) + tid * 4;                   \
        int p    = flat / 343;                                   \
        int e    = flat - p * 343;                               \
        int r    = e / 7;                                        \
        int xx_  = e - r * 7;                                    \
        int dst  = p * PATCH_H + r * ROW_H + xx_;                \
        float v4[4] = {(C).x, (C).y, (C).z, (C).w};              \
        _Pragma("unroll")                                        \
        for (int el = 0; el < 4; ++el) {                         \
            sm.tile[dst] = f2h(v4[el]);                          \
            ++dst; if (++xx_ == 7) { xx_ = 0; ++dst; }           \
        }                                                        \
    } while (0)

    {
        float4 buf[4];
#pragma unroll
        for (int k = 0; k < 4; ++k) buf[k] = src[k * TPB + tid];

#pragma unroll 1
        for (int it0 = 0; it0 < 20; it0 += 4) {     // processes iters 0..19
#pragma unroll
            for (int k = 0; k < 4; ++k) {
                float4 cur = buf[k];
                int idx = (it0 + 4 + k) * TPB + tid;
                if (idx > NF4 - 1) idx = NF4 - 1;   // clamp (safe dup load)
                buf[k] = src[idx];
                STORE4(it0 + k, cur);
            }
        }
        STORE4(20, buf[0]);                  // iter 20: 5120+tid < 5488, all valid
        if (tid < 112) STORE4(21, buf[1]);   // iter 21 partial: 5376+tid < 5488
    }
#undef STORE4
    __syncthreads();

    // ===================== per-thread conv1+conv2 (4-way task split) ========
    const unsigned int* __restrict__ P =
        reinterpret_cast<const unsigned int*>(sm.tile) + lane * PATCH_D;
    const float bb1 = b1[0];

    float a2[3][3][3];
    {
        const float init = (wid == 0) ? b2[0] : 0.f;   // bias added exactly once
#pragma unroll
        for (int a = 0; a < 3; ++a)
#pragma unroll
            for (int b = 0; b < 3; ++b)
#pragma unroll
                for (int c = 0; c < 3; ++c) a2[a][b][c] = init;
    }

    if      (wid == 0) run_tasks<0, 0, 1, 1>(P, wa, wb, wc, bb1, w2, a2);  // 7
    else if (wid == 1) run_tasks<1, 2, 2, 3>(P, wa, wb, wc, bb1, w2, a2);  // 7
    else if (wid == 2) run_tasks<2, 4, 3, 4>(P, wa, wb, wc, bb1, w2, a2);  // 6
    else               run_tasks<4, 0, 4, 4>(P, wa, wb, wc, bb1, w2, a2);  // 5

    __syncthreads();     // all tile reads complete before aliasing as `part`

    if (wid != 0) {
#pragma unroll
        for (int t = 0; t < 27; ++t)
            sm.part[wid - 1][lane][t] = a2[t / 9][(t / 3) % 3][t % 3];
    }
    __syncthreads();

    // ===================== combine + bilateral (wave 0 only) ================
    if (wid == 0) {
        const int n   = blk * PPB + lane;
        const int dd  = n / 9216;
        const int rem = n - dd * 9216;
        const int h   = rem / 96;
        const int w_  = rem - h * 96;

        float num = 0.f, den = 0.f;
#pragma unroll
        for (int dz = 0; dz < 3; ++dz)
#pragma unroll
            for (int dy = 0; dy < 3; ++dy)
#pragma unroll
                for (int dx = 0; dx < 3; ++dx) {
                    const int t = dz * 9 + dy * 3 + dx;
                    const float r2 = fmaxf(a2[dz][dy][dx] + sm.part[0][lane][t]
                                           + sm.part[1][lane][t]
                                           + sm.part[2][lane][t], 0.f);
                    const float wt = fmaf(dom[t], r2, 1e-10f);
                    const int yy = h - 1 + dy, xx = w_ - 1 + dx;
                    float xv = 0.f;
                    if (yy >= 0 && yy < 96 && xx >= 0 && xx < 96)
                        xv = x[(dd + 1 + dz) * 9216 + yy * 96 + xx];
                    num = fmaf(wt, xv, num);
                    den += wt;
                }
        out[n] = num / den;
    }
}

extern "C" void kernel_launch(void* const* d_in, const int* in_sizes, int n_in,
                              void* d_out, int out_size, void* d_ws, size_t ws_size,
                              hipStream_t stream) {
    const float* x     = (const float*)d_in[0];
    const float* dn    = (const float*)d_in[1];
    const float* guide = (const float*)d_in[2];
    const float* w1_d  = (const float*)d_in[3];
    const float* b1_d  = (const float*)d_in[4];
    const float* w2_d  = (const float*)d_in[5];
    const float* b2_d  = (const float*)d_in[6];
    const float* w1_r  = (const float*)d_in[7];
    const float* b1_r  = (const float*)d_in[8];
    const float* w2_r  = (const float*)d_in[9];
    const float* b2_r  = (const float*)d_in[10];
    float* out = (float*)d_out;
    float* dom = (float*)d_ws;   // 27 floats of scratch

    domain_branch_kernel<<<1, 128, 0, stream>>>(dn, w1_d, b1_d, w2_d, b2_d, dom);
    jbf_main_kernel<<<NBLK, TPB, 0, stream>>>(guide, x, w1_r, b1_r, w2_r,
                                              b2_r, dom, out);
}